// Round 1
// baseline (1535.257 us; speedup 1.0000x reference)
//
#include <hip/hip_runtime.h>
#include <math.h>

#define CUTOFF 5.0f
#define H 64
#define FIN 16
#define NLAYERS 3

// 1/sqrt(1 + 1e-3)  (BN inference, moving mean 0 / var 1)
#define BN_INV 0.999500374750f

__device__ __forceinline__ float fast_tanh(float x) {
    x = fminf(fmaxf(x, -15.f), 15.f);
    float e = __expf(2.f * x);
    return (e - 1.f) / (e + 1.f);
}

__device__ __forceinline__ float softplus_f(float x) {
    // stable: max(x,0) + log1p(exp(-|x|))
    return fmaxf(x, 0.f) + __logf(1.f + __expf(-fabsf(x)));
}

// Precompute rowsum(fW2[l]) and sum(fb2[l]):  fs = cut*(sum_h t_h * wsum_h + bsum)
__global__ void k_wsum(const float* __restrict__ fW2, const float* __restrict__ fb2,
                       float* __restrict__ wsum, float* __restrict__ bsum) {
    int tid = threadIdx.x;
    if (tid < NLAYERS * H) {
        int l = tid >> 6, hh = tid & 63;
        float s = 0.f;
        for (int j = 0; j < H; j++) s += fW2[l * H * H + hh * H + j];
        wsum[tid] = s;
    }
    if (tid < NLAYERS) {
        float s = 0.f;
        for (int j = 0; j < H; j++) s += fb2[tid * H + j];
        bsum[tid] = s;
    }
}

// h = x @ emb_W + emb_b    (wave per node; lane = output channel)
__global__ void k_embed(const float* __restrict__ x, const float* __restrict__ emb_W,
                        const float* __restrict__ emb_b, float* __restrict__ h, int N) {
    int lane = threadIdx.x & 63;
    int w = threadIdx.x >> 6;
    int node = blockIdx.x * 4 + w;
    if (node >= N) return;
    float acc = emb_b[lane];
#pragma unroll
    for (int k = 0; k < FIN; k++) acc += x[node * FIN + k] * emb_W[k * H + lane];
    h[node * H + lane] = acc;
}

// One wave per edge: lane h computes one tanh filter term, butterfly-reduce -> fs,
// then lane j atomically accumulates fs*h[col][j] into agg[row][j] (coalesced).
__global__ void k_edge(const int* __restrict__ ei, const float* __restrict__ dist,
                       const float* __restrict__ fW1, const float* __restrict__ fb1,
                       const float* __restrict__ wsum, const float* __restrict__ bsum,
                       const float* __restrict__ h, float* __restrict__ agg,
                       int E, int layer) {
    int lane = threadIdx.x & 63;
    int e = blockIdx.x * 4 + (threadIdx.x >> 6);
    if (e >= E) return;
    int row = ei[e];
    int col = ei[E + e];
    float d = dist[e];
    float scaled = d * (2.0f / CUTOFF) - 1.0f;
    float cut = (d <= CUTOFF) ? 0.5f * (__cosf(d * (3.14159265358979f / CUTOFF)) + 1.0f)
                              : 0.0f;
    int wi = layer * H + lane;
    float t = fast_tanh(scaled * fW1[wi] + fb1[wi]) * wsum[wi];
#pragma unroll
    for (int m = 32; m >= 1; m >>= 1) t += __shfl_xor(t, m, 64);
    float fs = cut * (t + bsum[layer]);
    atomicAdd(&agg[(size_t)row * H + lane], fs * h[(size_t)col * H + lane]);
}

// out = softplus(agg@iW1+ib1)@iW2+ib2; BN; h += out   (wave per node, LDS broadcast)
__global__ void k_node(const float* __restrict__ agg, const float* __restrict__ iW1,
                       const float* __restrict__ ib1, const float* __restrict__ iW2,
                       const float* __restrict__ ib2, const float* __restrict__ gamma,
                       const float* __restrict__ beta, float* __restrict__ h,
                       int N, int layer) {
    __shared__ float s_a[4][H];
    __shared__ float s_m[4][H];
    int lane = threadIdx.x & 63;
    int w = threadIdx.x >> 6;
    int node = blockIdx.x * 4 + w;
    bool active = node < N;
    float a = active ? agg[(size_t)node * H + lane] : 0.f;
    s_a[w][lane] = a;
    __syncthreads();
    const float* W1 = iW1 + layer * H * H;
    const float* W2 = iW2 + layer * H * H;
    float acc1 = ib1[layer * H + lane];
#pragma unroll 8
    for (int k = 0; k < H; k++) acc1 += s_a[w][k] * W1[k * H + lane];
    s_m[w][lane] = softplus_f(acc1);
    __syncthreads();
    float acc2 = ib2[layer * H + lane];
#pragma unroll 8
    for (int k = 0; k < H; k++) acc2 += s_m[w][k] * W2[k * H + lane];
    float out = acc2 * BN_INV * gamma[layer * H + lane] + beta[layer * H + lane];
    if (active) h[(size_t)node * H + lane] += out;
}

// gsum[j] += sum over assigned nodes of h[i][j]
__global__ void k_mean(const float* __restrict__ h, float* __restrict__ gsum, int N) {
    __shared__ float s_r[4][H];
    int lane = threadIdx.x & 63;
    int w = threadIdx.x >> 6;
    int wg = blockIdx.x * 4 + w;
    int stride = gridDim.x * 4;
    float local = 0.f;
    for (int i = wg; i < N; i += stride) local += h[(size_t)i * H + lane];
    s_r[w][lane] = local;
    __syncthreads();
    if (w == 0) {
        float s = s_r[0][lane] + s_r[1][lane] + s_r[2][lane] + s_r[3][lane];
        atomicAdd(&gsum[lane], s);
    }
}

// Final tiny MLP chain on one block of 64 threads.
__global__ void k_final(const float* __restrict__ gsum, const float* __restrict__ oW1,
                        const float* __restrict__ ob1, const float* __restrict__ og1,
                        const float* __restrict__ obt1, const float* __restrict__ oW2,
                        const float* __restrict__ ob2, const float* __restrict__ og2,
                        const float* __restrict__ obt2, const float* __restrict__ fin_W,
                        const float* __restrict__ fin_b, float* __restrict__ out, int N) {
    __shared__ float sg[H], su[H / 2], sv[H / 2];
    int j = threadIdx.x;
    sg[j] = gsum[j] / (float)N;
    __syncthreads();
    if (j < H / 2) {
        float acc = ob1[j];
        for (int k = 0; k < H; k++) acc += sg[k] * oW1[k * (H / 2) + j];
        su[j] = softplus_f(acc) * BN_INV * og1[j] + obt1[j];
    }
    __syncthreads();
    if (j < H / 2) {
        float acc = ob2[j];
        for (int k = 0; k < H / 2; k++) acc += su[k] * oW2[k * (H / 2) + j];
        sv[j] = softplus_f(acc) * BN_INV * og2[j] + obt2[j];
    }
    __syncthreads();
    if (j < 3) {
        float acc = fin_b[j];
        for (int k = 0; k < H / 2; k++) acc += sv[k] * fin_W[k * 3 + j];
        out[j] = acc;
    }
}

extern "C" void kernel_launch(void* const* d_in, const int* in_sizes, int n_in,
                              void* d_out, int out_size, void* d_ws, size_t ws_size,
                              hipStream_t stream) {
    const float* x      = (const float*)d_in[0];
    const int*   ei     = (const int*)d_in[1];
    const float* dist   = (const float*)d_in[2];
    /* d_in[3] edge_attr: unused by reference */
    const float* emb_W  = (const float*)d_in[4];
    const float* emb_b  = (const float*)d_in[5];
    const float* fW1    = (const float*)d_in[6];
    const float* fb1    = (const float*)d_in[7];
    const float* fW2    = (const float*)d_in[8];
    const float* fb2    = (const float*)d_in[9];
    const float* iW1    = (const float*)d_in[10];
    const float* ib1    = (const float*)d_in[11];
    const float* iW2    = (const float*)d_in[12];
    const float* ib2    = (const float*)d_in[13];
    const float* bn_g   = (const float*)d_in[14];
    const float* bn_b   = (const float*)d_in[15];
    const float* oW1    = (const float*)d_in[16];
    const float* ob1    = (const float*)d_in[17];
    const float* og1    = (const float*)d_in[18];
    const float* obt1   = (const float*)d_in[19];
    const float* oW2    = (const float*)d_in[20];
    const float* ob2    = (const float*)d_in[21];
    const float* og2    = (const float*)d_in[22];
    const float* obt2   = (const float*)d_in[23];
    const float* fin_W  = (const float*)d_in[24];
    const float* fin_b  = (const float*)d_in[25];
    float* out = (float*)d_out;

    int N = in_sizes[0] / FIN;
    int E = in_sizes[2];

    float* ws   = (float*)d_ws;
    float* h    = ws;                         // N*H
    float* agg  = ws + (size_t)N * H;         // N*H
    float* wsum = ws + (size_t)2 * N * H;     // L*H
    float* bsum = wsum + NLAYERS * H;         // L (+pad)
    float* gsum = bsum + 8;                   // H

    hipMemsetAsync(gsum, 0, H * sizeof(float), stream);
    k_wsum<<<1, 256, 0, stream>>>(fW2, fb2, wsum, bsum);

    int nb_node = (N + 3) / 4;
    k_embed<<<nb_node, 256, 0, stream>>>(x, emb_W, emb_b, h, N);

    int nb_edge = (E + 3) / 4;
    for (int l = 0; l < NLAYERS; l++) {
        hipMemsetAsync(agg, 0, (size_t)N * H * sizeof(float), stream);
        k_edge<<<nb_edge, 256, 0, stream>>>(ei, dist, fW1, fb1, wsum, bsum, h, agg, E, l);
        k_node<<<nb_node, 256, 0, stream>>>(agg, iW1, ib1, iW2, ib2, bn_g, bn_b, h, N, l);
    }

    k_mean<<<1024, 256, 0, stream>>>(h, gsum, N);
    k_final<<<1, 64, 0, stream>>>(gsum, oW1, ob1, og1, obt1, oW2, ob2, og2, obt2,
                                  fin_W, fin_b, out, N);
}